// Round 18
// baseline (72.336 us; speedup 1.0000x reference)
//
#include <hip/hip_runtime.h>
#include <hip/hip_bf16.h>

#define TT 36
#define NN 207
#define LN_EPS 1e-5f

typedef __attribute__((ext_vector_type(8))) short short8;
typedef __attribute__((ext_vector_type(4))) float f32x4;

__device__ __forceinline__ unsigned short f2b(float f) {
    union { __hip_bfloat16 h; unsigned short u; } x;
    x.h = __float2bfloat16(f);
    return x.u;
}
__device__ __forceinline__ short8 s8(uint4 u) { union { uint4 a; short8 b; } x; x.a = u; return x.b; }

// ws layout (ushort units): [0..1023] Mt [32][32]; [1024..5119] Wv16 [64][64]; [5120..9215] Wo16 [64][64]
// Parallel prep: 12 blocks. 0-3: Wv cvt; 4-7: Wo cvt; 8-11: Mt quarters.
// Mt scale includes log2(e) so main kernel uses raw exp2.
__global__ __launch_bounds__(512) void prep_kernel(
    const float* __restrict__ Wv, const float* __restrict__ Wo,
    const float* __restrict__ cqw, const float* __restrict__ cqb,
    const float* __restrict__ ckw, unsigned short* __restrict__ ws)
{
    const int tid = threadIdx.x;
    const int blk = blockIdx.x;
    if (blk < 4) {
        int base = blk * 1024;
        for (int i = tid; i < 1024; i += 512) ws[1024 + base + i] = f2b(Wv[base + i]);
    } else if (blk < 8) {
        int base = (blk - 4) * 1024;
        for (int i = tid; i < 1024; i += 512) ws[5120 + base + i] = f2b(Wo[base + i]);
    } else {
        const float SCALE = 0.125f * 1.44269504088896340736f;   // /sqrt(64) * log2(e)
        int u0 = (blk - 8) * 256;
        for (int u = u0 + tid; u < u0 + 256; u += 512) {
            int j2 = u >> 5, jp = u & 31;
            float acc = 0.f;
            if (j2 < 24 && jp < 25) {
                int wkc = (j2 & 7) * 3 + (j2 >> 3);
                if (jp < 24) {
                    int wqc = (jp & 7) * 3 + (jp >> 3);
                    for (int c = 0; c < 64; ++c) acc += cqw[c * 24 + wqc] * ckw[c * 24 + wkc];
                } else {
                    for (int c = 0; c < 64; ++c) acc += cqb[c] * ckw[c * 24 + wkc];
                }
                acc *= SCALE;
            }
            ws[u] = f2b(acc);
        }
    }
}

__global__ __launch_bounds__(512, 4) void fused_attn18(
    const float* __restrict__ X, const float* __restrict__ Qg,
    const float* __restrict__ Kg, const float* __restrict__ Vg,
    const float* __restrict__ bv, const float* __restrict__ bo,
    const float* __restrict__ gam, const float* __restrict__ bet,
    const unsigned short* __restrict__ ws,
    float* __restrict__ out)
{
    // single carved SMEM block, 39,680 B -> 4 blocks/CU
    __shared__ __align__(16) unsigned char SMEM[39680];
    unsigned short* Qs  = (unsigned short*)(SMEM);            // [40][72] bf16 (rows 36-39 zero)
    unsigned short* Ks  = (unsigned short*)(SMEM + 5760);     // [40][72]
    unsigned short* VhT = (unsigned short*)(SMEM + 11520);    // [64][40], t=36..39 zero
    unsigned short* P_s = (unsigned short*)(SMEM + 16640);    // Pbuf: per-wave [36][40] Z/P + ctx slot
    unsigned short* Vs  = P_s;                                // [36][72] bf16 staging (Pbuf head)
    float*          OutS = (float*)SMEM;                      // [36][68] f32, aliases dead Qs/Ks after barrier C

    const unsigned short* MtG = ws;          // [32][32]
    const unsigned short* WvG = ws + 1024;   // [64][64]
    const unsigned short* WoG = ws + 5120;   // [64][64]

    const int tid  = threadIdx.x;
    const int lane = tid & 63;
    const int wave = tid >> 6;
    const int g    = lane >> 4, c15 = lane & 15;
    const int b    = blockIdx.x / NN;
    const int n    = blockIdx.x % NN;
    const uint4 z4 = {0u, 0u, 0u, 0u};

    // cheap scalar hoists
    const float gamr = gam[lane], betr = bet[lane];
    const int ot_ep = (wave < 4) ? wave : wave - 4;
    const float4 bo4 = ((const float4*)bo)[ot_ep * 4 + g];
    const float bvv = bv[ot_ep * 16 + c15];   // VhProj ct == ot_ep

    // ================= staging =================
    const float4* Q4 = (const float4*)(Qg + (size_t)(b * TT * NN + n) * 64);
    const float4* K4 = (const float4*)(Kg + (size_t)(b * TT * NN + n) * 64);
    const float4* V4 = (const float4*)(Vg + (size_t)(b * TT * NN + n) * 64);
    for (int idx = tid; idx < TT * 16; idx += 512) {
        int t = idx >> 4, o = idx & 15;
        float4 q = Q4[t * 3312 + o];
        float4 k = K4[t * 3312 + o];
        float4 v = V4[t * 3312 + o];
        ushort4 qp = {f2b(q.x), f2b(q.y), f2b(q.z), f2b(q.w)};
        ushort4 kp = {f2b(k.x), f2b(k.y), f2b(k.z), f2b(k.w)};
        ushort4 vp = {f2b(v.x), f2b(v.y), f2b(v.z), f2b(v.w)};
        *(ushort4*)&Qs[t * 72 + o * 4] = qp;
        *(ushort4*)&Ks[t * 72 + o * 4] = kp;
        *(ushort4*)&Vs[t * 72 + o * 4] = vp;
    }
    for (int idx = tid; idx < 72; idx += 512) {     // zero Q/K pad rows 36-39
        if (idx < 36) ((uint4*)&Qs[36 * 72])[idx] = z4;
        else          ((uint4*)&Ks[36 * 72])[idx - 36] = z4;
    }
    if (tid < 64) *(uint2*)&VhT[tid * 40 + 36] = make_uint2(0u, 0u);
    __syncthreads();   // barrier A: staging complete

    // ================= Vh proj (MFMA -> VhT transposed), reads Vs =================
    {
        #pragma unroll
        for (int tt = 0; tt < 2; ++tt) {
            int rt, ct;
            if (wave < 4) { rt = tt * 2; ct = wave; }
            else { if (tt) break; rt = 1; ct = wave - 4; }
            f32x4 d = {bvv, bvv, bvv, bvv};
            int rc = min(rt * 16 + c15, 35);
            uint4 A0 = *(const uint4*)&Vs[rc * 72 + g * 8];
            uint4 A1 = *(const uint4*)&Vs[rc * 72 + 32 + g * 8];
            uint4 B0 = *(const uint4*)&WvG[(ct * 16 + c15) * 64 + g * 8];
            uint4 B1 = *(const uint4*)&WvG[(ct * 16 + c15) * 64 + 32 + g * 8];
            d = __builtin_amdgcn_mfma_f32_16x16x32_bf16(s8(A0), s8(B0), d, 0, 0, 0);
            d = __builtin_amdgcn_mfma_f32_16x16x32_bf16(s8(A1), s8(B1), d, 0, 0, 0);
            int ts = rt * 16 + g * 4;
            if (ts < 36) {
                ushort4 o4 = {f2b(d[0]), f2b(d[1]), f2b(d[2]), f2b(d[3])};
                *(ushort4*)&VhT[(ct * 16 + c15) * 40 + ts] = o4;
            }
        }
    }
    __syncthreads();   // barrier A2: Vs dead; Pbuf now owned by per-wave Z/P

    // ---- X-residual prefetch: issue ~2 phases ahead of out-proj use ----
    float4 xv0, xv1;
    {
        const int nt0 = (wave < 4) ? 0 : 1;
        const int t0  = nt0 * 16 + c15;
        xv0 = *(const float4*)&X[((size_t)(b * TT + min(t0, 35)) * NN + n) * 64 + ot_ep * 16 + g * 4];
        xv1 = make_float4(0.f, 0.f, 0.f, 0.f);
        if (wave < 4) {
            const int t1 = 32 + c15;
            xv1 = *(const float4*)&X[((size_t)(b * TT + min(t1, 35)) * NN + n) * 64 + ot_ep * 16 + g * 4];
        }
    }

    // ---- barrier-free stretch: Z' -> S -> ctx (all wave-private LDS) ----

    // ================= Z' = Mt @ Aq^T (packed row stores into own Ph) =================
    const int h8 = wave * 8;
    unsigned short* Ph = P_s + wave * 1440;     // [36][40] Z, then P; ctx slot at +1152
    {
        uint4 Af[2];
        #pragma unroll
        for (int mt = 0; mt < 2; ++mt)
            Af[mt] = *(const uint4*)&MtG[(mt * 16 + c15) * 32 + g * 8];
        #pragma unroll
        for (int qt = 0; qt < 3; ++qt) {
            uint4 bq;
            if (g == 3) { bq = z4; bq.x = 0x00003F80u; }   // bias feature f=24 -> 1.0
            else {
                int row = qt * 16 + c15 + g - 2;
                int rcq = min(max(row, 0), 39);
                bq = *(const uint4*)&Qs[rcq * 72 + h8];
                if (row < 0) bq = z4;
            }
            const int q = qt * 16 + c15;
            #pragma unroll
            for (int mt = 0; mt < 2; ++mt) {
                f32x4 zero = {0.f, 0.f, 0.f, 0.f};
                f32x4 d = __builtin_amdgcn_mfma_f32_16x16x32_bf16(s8(Af[mt]), s8(bq), zero, 0, 0, 0);
                if (q < 36) {
                    ushort4 o4 = {f2b(d[0]), f2b(d[1]), f2b(d[2]), f2b(d[3])};
                    *(ushort4*)&Ph[q * 40 + mt * 16 + g * 4] = o4;
                }
            }
        }
    }

    // ================= W = Ak @ Z^T, exp2 -> P packed (wave-private, no barrier) =================
    {
        uint4 Ak[3], Zq[3];
        #pragma unroll
        for (int kt = 0; kt < 3; ++kt) {
            uint4 v = z4;
            if (g < 3) {
                int row = kt * 16 + c15 + g - 2;
                int rck = min(max(row, 0), 39);
                v = *(const uint4*)&Ks[rck * 72 + h8];
                if (row < 0) v = z4;
            }
            Ak[kt] = v;
        }
        #pragma unroll
        for (int qt = 0; qt < 3; ++qt) {
            int rcq = min(qt * 16 + c15, 35);
            Zq[qt] = *(const uint4*)&Ph[rcq * 40 + g * 8];
        }
        #pragma unroll
        for (int qt = 0; qt < 3; ++qt) {
            const int q = qt * 16 + c15;
            const bool qok = (qt < 2) || (c15 < 4);
            #pragma unroll
            for (int kt = 0; kt < 3; ++kt) {
                const int k0 = kt * 16 + g * 4;
                const bool can = qok && ((kt < 2) || (g < 2));
                if (kt <= qt) {
                    f32x4 zero = {0.f, 0.f, 0.f, 0.f};
                    f32x4 s = __builtin_amdgcn_mfma_f32_16x16x32_bf16(s8(Ak[kt]), s8(Zq[qt]), zero, 0, 0, 0);
                    if (can) {
                        ushort4 o4;
                        if (kt == qt) {
                            o4.x = (k0 + 0 <= q) ? f2b(__builtin_amdgcn_exp2f(s[0])) : (unsigned short)0;
                            o4.y = (k0 + 1 <= q) ? f2b(__builtin_amdgcn_exp2f(s[1])) : (unsigned short)0;
                            o4.z = (k0 + 2 <= q) ? f2b(__builtin_amdgcn_exp2f(s[2])) : (unsigned short)0;
                            o4.w = (k0 + 3 <= q) ? f2b(__builtin_amdgcn_exp2f(s[3])) : (unsigned short)0;
                        } else {
                            o4.x = f2b(__builtin_amdgcn_exp2f(s[0]));
                            o4.y = f2b(__builtin_amdgcn_exp2f(s[1]));
                            o4.z = f2b(__builtin_amdgcn_exp2f(s[2]));
                            o4.w = f2b(__builtin_amdgcn_exp2f(s[3]));
                        }
                        *(ushort4*)&Ph[q * 40 + k0] = o4;
                    }
                } else {
                    if (can) {
                        ushort4 zz = {0, 0, 0, 0};
                        *(ushort4*)&Ph[q * 40 + k0] = zz;
                    }
                }
            }
        }
    }

    // ========= ctx = [Vh|1]^T @ P^T -> own ctx slot [36][8] at Ph+1152 =========
    // (ctx slot overlaps P rows >=28.8, so ALL P B-frags are pre-loaded first)
    {
        const unsigned ONE2 = 0x3F803F80u;
        uint4 A0, A1;
        if (c15 == 8) {
            A0 = make_uint4(ONE2, ONE2, ONE2, ONE2);
            A1 = (g == 0) ? make_uint4(ONE2, ONE2, 0u, 0u) : z4;
        } else if (c15 < 8) {
            A0 = *(const uint4*)&VhT[(h8 + c15) * 40 + g * 8];
            A1 = (g == 0) ? *(const uint4*)&VhT[(h8 + c15) * 40 + 32] : z4;
        } else { A0 = z4; A1 = z4; }
        uint4 PB0[3], PB1[3];
        #pragma unroll
        for (int qt = 0; qt < 3; ++qt) {
            int rcq = min(qt * 16 + c15, 35);
            PB0[qt] = *(const uint4*)&Ph[rcq * 40 + g * 8];
            PB1[qt] = (g == 0) ? *(const uint4*)&Ph[rcq * 40 + 32] : z4;
        }
        unsigned short* PhC = Ph + 1152;   // [36][8] ctx slot
        #pragma unroll
        for (int qt = 0; qt < 3; ++qt) {
            f32x4 d = {0.f, 0.f, 0.f, 0.f};
            d = __builtin_amdgcn_mfma_f32_16x16x32_bf16(s8(A0), s8(PB0[qt]), d, 0, 0, 0);
            d = __builtin_amdgcn_mfma_f32_16x16x32_bf16(s8(A1), s8(PB1[qt]), d, 0, 0, 0);
            float es = __shfl(d[0], 32 + c15);     // row 8 holds esum for this q
            float rcp = __frcp_rn(es);
            const int q = qt * 16 + c15;
            if (g < 2 && ((qt < 2) || (c15 < 4))) {
                ushort4 o4 = {f2b(d[0] * rcp), f2b(d[1] * rcp), f2b(d[2] * rcp), f2b(d[3] * rcp)};
                *(ushort4*)&PhC[q * 8 + g * 4] = o4;
            }
        }
    }
    __syncthreads();   // barrier C: all ctx slots written; Qs/Ks/VhT dead -> OutS owns SMEM head

    // ======= Out' = Wo @ Ctx^T + bo + X(prefetched) -> OutS =======
    {
        const int ot = ot_ep;
        uint4 A0 = *(const uint4*)&WoG[(ot * 16 + c15) * 64 + g * 8];
        uint4 A1 = *(const uint4*)&WoG[(ot * 16 + c15) * 64 + 32 + g * 8];
        #pragma unroll
        for (int pass = 0; pass < 2; ++pass) {
            int nt;
            float4 xv;
            if (wave < 4) { nt = pass * 2; xv = pass ? xv1 : xv0; }
            else { if (pass) break; nt = 1; xv = xv0; }
            int rct = min(nt * 16 + c15, 35);
            uint4 B0 = *(const uint4*)&P_s[g * 1440 + 1152 + rct * 8];         // head g
            uint4 B1 = *(const uint4*)&P_s[(4 + g) * 1440 + 1152 + rct * 8];   // head 4+g
            f32x4 d = {bo4.x, bo4.y, bo4.z, bo4.w};
            d = __builtin_amdgcn_mfma_f32_16x16x32_bf16(s8(A0), s8(B0), d, 0, 0, 0);
            d = __builtin_amdgcn_mfma_f32_16x16x32_bf16(s8(A1), s8(B1), d, 0, 0, 0);
            const int t = nt * 16 + c15;
            const int o0 = ot * 16 + g * 4;
            if (t < 36) {
                float4 ov = {d[0] + xv.x, d[1] + xv.y, d[2] + xv.z, d[3] + xv.w};
                *(float4*)&OutS[t * 68 + o0] = ov;
            }
        }
    }
    __syncthreads();   // barrier D

    // ================= LayerNorm (scalar, proven) =================
    {
        for (int t = wave; t < TT; t += 8) {
            float acc = OutS[t * 68 + lane];
            float s1 = acc, s2 = acc * acc;
            #pragma unroll
            for (int off = 32; off; off >>= 1) {
                s1 += __shfl_xor(s1, off);
                s2 += __shfl_xor(s2, off);
            }
            float mu  = s1 * (1.f / 64.f);
            float var = s2 * (1.f / 64.f) - mu * mu;
            size_t gi = ((size_t)(b * TT + t) * NN + n) * 64 + lane;
            out[gi] = (acc - mu) * rsqrtf(var + LN_EPS) * gamr + betr;
        }
    }
}

extern "C" void kernel_launch(void* const* d_in, const int* in_sizes, int n_in,
                              void* d_out, int out_size, void* d_ws, size_t ws_size,
                              hipStream_t stream) {
    const float* X   = (const float*)d_in[0];
    const float* Q   = (const float*)d_in[1];
    const float* K   = (const float*)d_in[2];
    const float* V   = (const float*)d_in[3];
    const float* Wv  = (const float*)d_in[4];
    const float* bv  = (const float*)d_in[5];
    const float* Wo  = (const float*)d_in[6];
    const float* bo  = (const float*)d_in[7];
    const float* cqw = (const float*)d_in[8];
    const float* cqb = (const float*)d_in[9];
    const float* ckw = (const float*)d_in[10];
    // d_in[11] (conv_k_b) cancels in softmax -> unused
    const float* gam = (const float*)d_in[12];
    const float* bet = (const float*)d_in[13];
    float* out = (float*)d_out;
    unsigned short* ws = (unsigned short*)d_ws;

    hipLaunchKernelGGL(prep_kernel, dim3(12), dim3(512), 0, stream, Wv, Wo, cqw, cqb, ckw, ws);
    hipLaunchKernelGGL(fused_attn18, dim3(16 * NN), dim3(512), 0, stream,
                       X, Q, K, V, bv, bo, gam, bet, ws, out);
}

// Round 19
// 69.957 us; speedup vs baseline: 1.0340x; 1.0340x over previous
//
#include <hip/hip_runtime.h>
#include <hip/hip_bf16.h>

#define TT 36
#define NN 207
#define LN_EPS 1e-5f

typedef __attribute__((ext_vector_type(8))) short short8;
typedef __attribute__((ext_vector_type(4))) float f32x4;

__device__ __forceinline__ unsigned short f2b(float f) {
    union { __hip_bfloat16 h; unsigned short u; } x;
    x.h = __float2bfloat16(f);
    return x.u;
}
__device__ __forceinline__ short8 s8(uint4 u) { union { uint4 a; short8 b; } x; x.a = u; return x.b; }

// ws layout (ushort units): [0..1023] Mt [32][32]; [1024..5119] Wv16 [64][64]; [5120..9215] Wo16 [64][64]
// Parallel prep: 12 blocks. Mt scale includes log2(e) so main kernel uses raw exp2.
__global__ __launch_bounds__(512) void prep_kernel(
    const float* __restrict__ Wv, const float* __restrict__ Wo,
    const float* __restrict__ cqw, const float* __restrict__ cqb,
    const float* __restrict__ ckw, unsigned short* __restrict__ ws)
{
    const int tid = threadIdx.x;
    const int blk = blockIdx.x;
    if (blk < 4) {
        int base = blk * 1024;
        for (int i = tid; i < 1024; i += 512) ws[1024 + base + i] = f2b(Wv[base + i]);
    } else if (blk < 8) {
        int base = (blk - 4) * 1024;
        for (int i = tid; i < 1024; i += 512) ws[5120 + base + i] = f2b(Wo[base + i]);
    } else {
        const float SCALE = 0.125f * 1.44269504088896340736f;   // /sqrt(64) * log2(e)
        int u0 = (blk - 8) * 256;
        for (int u = u0 + tid; u < u0 + 256; u += 512) {
            int j2 = u >> 5, jp = u & 31;
            float acc = 0.f;
            if (j2 < 24 && jp < 25) {
                int wkc = (j2 & 7) * 3 + (j2 >> 3);
                if (jp < 24) {
                    int wqc = (jp & 7) * 3 + (jp >> 3);
                    for (int c = 0; c < 64; ++c) acc += cqw[c * 24 + wqc] * ckw[c * 24 + wkc];
                } else {
                    for (int c = 0; c < 64; ++c) acc += cqb[c] * ckw[c * 24 + wkc];
                }
                acc *= SCALE;
            }
            ws[u] = f2b(acc);
        }
    }
}

__global__ __launch_bounds__(512, 4) void fused_attn19(
    const float* __restrict__ X, const float* __restrict__ Qg,
    const float* __restrict__ Kg, const float* __restrict__ Vg,
    const float* __restrict__ bv, const float* __restrict__ bo,
    const float* __restrict__ gam, const float* __restrict__ bet,
    const unsigned short* __restrict__ ws,
    float* __restrict__ out)
{
    // single carved SMEM block, 39,680 B -> 4 blocks/CU
    __shared__ __align__(16) unsigned char SMEM[39680];
    unsigned short* Qs  = (unsigned short*)(SMEM);            // [40][72] bf16 (rows 36-39 zero)
    unsigned short* Ks  = (unsigned short*)(SMEM + 5760);     // [40][72]
    unsigned short* VhT = (unsigned short*)(SMEM + 11520);    // [64][40], t=36..39 zero
    unsigned short* P_s = (unsigned short*)(SMEM + 16640);    // Pbuf: per-wave [36][40] Z/P + ctx slot
    unsigned short* Vs  = P_s;                                // [36][72] bf16 staging (Pbuf head)
    float*          OutS = (float*)SMEM;                      // [36][68] f32, aliases dead Qs/Ks after barrier C

    const unsigned short* MtG = ws;          // [32][32]
    const unsigned short* WvG = ws + 1024;   // [64][64]
    const unsigned short* WoG = ws + 5120;   // [64][64]

    const int tid  = threadIdx.x;
    const int lane = tid & 63;
    const int wave = tid >> 6;
    const int g    = lane >> 4, c15 = lane & 15;
    const int b    = blockIdx.x / NN;
    const int n    = blockIdx.x % NN;
    const uint4 z4 = {0u, 0u, 0u, 0u};

    // cheap scalar hoists
    const float gamr = gam[lane], betr = bet[lane];
    const int ot_ep = (wave < 4) ? wave : wave - 4;
    const float4 bo4 = ((const float4*)bo)[ot_ep * 4 + g];

    // ================= staging =================
    const float4* Q4 = (const float4*)(Qg + (size_t)(b * TT * NN + n) * 64);
    const float4* K4 = (const float4*)(Kg + (size_t)(b * TT * NN + n) * 64);
    const float4* V4 = (const float4*)(Vg + (size_t)(b * TT * NN + n) * 64);
    for (int idx = tid; idx < TT * 16; idx += 512) {
        int t = idx >> 4, o = idx & 15;
        float4 q = Q4[t * 3312 + o];
        float4 k = K4[t * 3312 + o];
        float4 v = V4[t * 3312 + o];
        ushort4 qp = {f2b(q.x), f2b(q.y), f2b(q.z), f2b(q.w)};
        ushort4 kp = {f2b(k.x), f2b(k.y), f2b(k.z), f2b(k.w)};
        ushort4 vp = {f2b(v.x), f2b(v.y), f2b(v.z), f2b(v.w)};
        *(ushort4*)&Qs[t * 72 + o * 4] = qp;
        *(ushort4*)&Ks[t * 72 + o * 4] = kp;
        *(ushort4*)&Vs[t * 72 + o * 4] = vp;
    }
    for (int idx = tid; idx < 72; idx += 512) {     // zero Q/K pad rows 36-39
        if (idx < 36) ((uint4*)&Qs[36 * 72])[idx] = z4;
        else          ((uint4*)&Ks[36 * 72])[idx - 36] = z4;
    }
    if (tid < 64) *(uint2*)&VhT[tid * 40 + 36] = make_uint2(0u, 0u);
    __syncthreads();   // barrier A: staging complete

    // ================= Vh proj (MFMA -> VhT transposed), reads Vs =================
    {
        #pragma unroll
        for (int tt = 0; tt < 2; ++tt) {
            int rt, ct;
            if (wave < 4) { rt = tt * 2; ct = wave; }
            else { if (tt) break; rt = 1; ct = wave - 4; }
            float bvv = bv[ct * 16 + c15];
            f32x4 d = {bvv, bvv, bvv, bvv};
            int rc = min(rt * 16 + c15, 35);
            uint4 A0 = *(const uint4*)&Vs[rc * 72 + g * 8];
            uint4 A1 = *(const uint4*)&Vs[rc * 72 + 32 + g * 8];
            uint4 B0 = *(const uint4*)&WvG[(ct * 16 + c15) * 64 + g * 8];
            uint4 B1 = *(const uint4*)&WvG[(ct * 16 + c15) * 64 + 32 + g * 8];
            d = __builtin_amdgcn_mfma_f32_16x16x32_bf16(s8(A0), s8(B0), d, 0, 0, 0);
            d = __builtin_amdgcn_mfma_f32_16x16x32_bf16(s8(A1), s8(B1), d, 0, 0, 0);
            int ts = rt * 16 + g * 4;
            if (ts < 36) {
                ushort4 o4 = {f2b(d[0]), f2b(d[1]), f2b(d[2]), f2b(d[3])};
                *(ushort4*)&VhT[(ct * 16 + c15) * 40 + ts] = o4;
            }
        }
    }
    __syncthreads();   // barrier A2: Vs dead; Pbuf now owned by per-wave Z/P
    // ---- barrier-free stretch: Z' -> S -> ctx (all wave-private LDS) ----

    // ================= Z' = Mt @ Aq^T (packed row stores into own Ph) =================
    const int h8 = wave * 8;
    unsigned short* Ph = P_s + wave * 1440;     // [36][40] Z, then P; ctx slot at +1152
    {
        uint4 Af[2];
        #pragma unroll
        for (int mt = 0; mt < 2; ++mt)
            Af[mt] = *(const uint4*)&MtG[(mt * 16 + c15) * 32 + g * 8];
        #pragma unroll
        for (int qt = 0; qt < 3; ++qt) {
            uint4 bq;
            if (g == 3) { bq = z4; bq.x = 0x00003F80u; }   // bias feature f=24 -> 1.0
            else {
                int row = qt * 16 + c15 + g - 2;
                int rcq = min(max(row, 0), 39);
                bq = *(const uint4*)&Qs[rcq * 72 + h8];
                if (row < 0) bq = z4;
            }
            const int q = qt * 16 + c15;
            #pragma unroll
            for (int mt = 0; mt < 2; ++mt) {
                f32x4 zero = {0.f, 0.f, 0.f, 0.f};
                f32x4 d = __builtin_amdgcn_mfma_f32_16x16x32_bf16(s8(Af[mt]), s8(bq), zero, 0, 0, 0);
                if (q < 36) {
                    ushort4 o4 = {f2b(d[0]), f2b(d[1]), f2b(d[2]), f2b(d[3])};
                    *(ushort4*)&Ph[q * 40 + mt * 16 + g * 4] = o4;
                }
            }
        }
    }

    // ================= W = Ak @ Z^T, exp2 -> P packed (wave-private, no barrier) =================
    {
        uint4 Ak[3], Zq[3];
        #pragma unroll
        for (int kt = 0; kt < 3; ++kt) {
            uint4 v = z4;
            if (g < 3) {
                int row = kt * 16 + c15 + g - 2;
                int rck = min(max(row, 0), 39);
                v = *(const uint4*)&Ks[rck * 72 + h8];
                if (row < 0) v = z4;
            }
            Ak[kt] = v;
        }
        #pragma unroll
        for (int qt = 0; qt < 3; ++qt) {
            int rcq = min(qt * 16 + c15, 35);
            Zq[qt] = *(const uint4*)&Ph[rcq * 40 + g * 8];
        }
        #pragma unroll
        for (int qt = 0; qt < 3; ++qt) {
            const int q = qt * 16 + c15;
            const bool qok = (qt < 2) || (c15 < 4);
            #pragma unroll
            for (int kt = 0; kt < 3; ++kt) {
                const int k0 = kt * 16 + g * 4;
                const bool can = qok && ((kt < 2) || (g < 2));
                if (kt <= qt) {
                    f32x4 zero = {0.f, 0.f, 0.f, 0.f};
                    f32x4 s = __builtin_amdgcn_mfma_f32_16x16x32_bf16(s8(Ak[kt]), s8(Zq[qt]), zero, 0, 0, 0);
                    if (can) {
                        ushort4 o4;
                        if (kt == qt) {
                            o4.x = (k0 + 0 <= q) ? f2b(__builtin_amdgcn_exp2f(s[0])) : (unsigned short)0;
                            o4.y = (k0 + 1 <= q) ? f2b(__builtin_amdgcn_exp2f(s[1])) : (unsigned short)0;
                            o4.z = (k0 + 2 <= q) ? f2b(__builtin_amdgcn_exp2f(s[2])) : (unsigned short)0;
                            o4.w = (k0 + 3 <= q) ? f2b(__builtin_amdgcn_exp2f(s[3])) : (unsigned short)0;
                        } else {
                            o4.x = f2b(__builtin_amdgcn_exp2f(s[0]));
                            o4.y = f2b(__builtin_amdgcn_exp2f(s[1]));
                            o4.z = f2b(__builtin_amdgcn_exp2f(s[2]));
                            o4.w = f2b(__builtin_amdgcn_exp2f(s[3]));
                        }
                        *(ushort4*)&Ph[q * 40 + k0] = o4;
                    }
                } else {
                    if (can) {
                        ushort4 zz = {0, 0, 0, 0};
                        *(ushort4*)&Ph[q * 40 + k0] = zz;
                    }
                }
            }
        }
    }

    // ========= ctx = [Vh|1]^T @ P^T -> own ctx slot [36][8] at Ph+1152 =========
    {
        const unsigned ONE2 = 0x3F803F80u;
        uint4 A0, A1;
        if (c15 == 8) {
            A0 = make_uint4(ONE2, ONE2, ONE2, ONE2);
            A1 = (g == 0) ? make_uint4(ONE2, ONE2, 0u, 0u) : z4;
        } else if (c15 < 8) {
            A0 = *(const uint4*)&VhT[(h8 + c15) * 40 + g * 8];
            A1 = (g == 0) ? *(const uint4*)&VhT[(h8 + c15) * 40 + 32] : z4;
        } else { A0 = z4; A1 = z4; }
        uint4 PB0[3], PB1[3];
        #pragma unroll
        for (int qt = 0; qt < 3; ++qt) {
            int rcq = min(qt * 16 + c15, 35);
            PB0[qt] = *(const uint4*)&Ph[rcq * 40 + g * 8];
            PB1[qt] = (g == 0) ? *(const uint4*)&Ph[rcq * 40 + 32] : z4;
        }
        unsigned short* PhC = Ph + 1152;   // [36][8] ctx slot
        #pragma unroll
        for (int qt = 0; qt < 3; ++qt) {
            f32x4 d = {0.f, 0.f, 0.f, 0.f};
            d = __builtin_amdgcn_mfma_f32_16x16x32_bf16(s8(A0), s8(PB0[qt]), d, 0, 0, 0);
            d = __builtin_amdgcn_mfma_f32_16x16x32_bf16(s8(A1), s8(PB1[qt]), d, 0, 0, 0);
            float es = __shfl(d[0], 32 + c15);     // row 8 holds esum for this q
            float rcp = __frcp_rn(es);
            const int q = qt * 16 + c15;
            if (g < 2 && ((qt < 2) || (c15 < 4))) {
                ushort4 o4 = {f2b(d[0] * rcp), f2b(d[1] * rcp), f2b(d[2] * rcp), f2b(d[3] * rcp)};
                *(ushort4*)&PhC[q * 8 + g * 4] = o4;
            }
        }
    }
    __syncthreads();   // barrier C: all ctx slots written; Qs/Ks/VhT dead -> OutS owns SMEM head

    // ======= Out' = Wo @ Ctx^T + bo + X -> OutS (B-frags from waves g and 4+g) =======
    {
        const int ot = ot_ep;
        uint4 A0 = *(const uint4*)&WoG[(ot * 16 + c15) * 64 + g * 8];
        uint4 A1 = *(const uint4*)&WoG[(ot * 16 + c15) * 64 + 32 + g * 8];
        #pragma unroll
        for (int pass = 0; pass < 2; ++pass) {
            int nt;
            if (wave < 4) nt = pass * 2;
            else { if (pass) break; nt = 1; }
            int rct = min(nt * 16 + c15, 35);
            uint4 B0 = *(const uint4*)&P_s[g * 1440 + 1152 + rct * 8];         // head g
            uint4 B1 = *(const uint4*)&P_s[(4 + g) * 1440 + 1152 + rct * 8];   // head 4+g
            f32x4 d = {bo4.x, bo4.y, bo4.z, bo4.w};
            d = __builtin_amdgcn_mfma_f32_16x16x32_bf16(s8(A0), s8(B0), d, 0, 0, 0);
            d = __builtin_amdgcn_mfma_f32_16x16x32_bf16(s8(A1), s8(B1), d, 0, 0, 0);
            const int t = nt * 16 + c15;
            const int o0 = ot * 16 + g * 4;
            if (t < 36) {
                size_t gi = ((size_t)(b * TT + t) * NN + n) * 64 + o0;
                float4 xv = *(const float4*)&X[gi];
                float4 ov = {d[0] + xv.x, d[1] + xv.y, d[2] + xv.z, d[3] + xv.w};
                *(float4*)&OutS[t * 68 + o0] = ov;
            }
        }
    }
    __syncthreads();   // barrier D

    // ================= LayerNorm (scalar, proven) =================
    {
        for (int t = wave; t < TT; t += 8) {
            float acc = OutS[t * 68 + lane];
            float s1 = acc, s2 = acc * acc;
            #pragma unroll
            for (int off = 32; off; off >>= 1) {
                s1 += __shfl_xor(s1, off);
                s2 += __shfl_xor(s2, off);
            }
            float mu  = s1 * (1.f / 64.f);
            float var = s2 * (1.f / 64.f) - mu * mu;
            size_t gi = ((size_t)(b * TT + t) * NN + n) * 64 + lane;
            out[gi] = (acc - mu) * rsqrtf(var + LN_EPS) * gamr + betr;
        }
    }
}

extern "C" void kernel_launch(void* const* d_in, const int* in_sizes, int n_in,
                              void* d_out, int out_size, void* d_ws, size_t ws_size,
                              hipStream_t stream) {
    const float* X   = (const float*)d_in[0];
    const float* Q   = (const float*)d_in[1];
    const float* K   = (const float*)d_in[2];
    const float* V   = (const float*)d_in[3];
    const float* Wv  = (const float*)d_in[4];
    const float* bv  = (const float*)d_in[5];
    const float* Wo  = (const float*)d_in[6];
    const float* bo  = (const float*)d_in[7];
    const float* cqw = (const float*)d_in[8];
    const float* cqb = (const float*)d_in[9];
    const float* ckw = (const float*)d_in[10];
    // d_in[11] (conv_k_b) cancels in softmax -> unused
    const float* gam = (const float*)d_in[12];
    const float* bet = (const float*)d_in[13];
    float* out = (float*)d_out;
    unsigned short* ws = (unsigned short*)d_ws;

    hipLaunchKernelGGL(prep_kernel, dim3(12), dim3(512), 0, stream, Wv, Wo, cqw, cqb, ckw, ws);
    hipLaunchKernelGGL(fused_attn19, dim3(16 * NN), dim3(512), 0, stream,
                       X, Q, K, V, bv, bo, gam, bet, ws, out);
}